// Round 6
// baseline (398.726 us; speedup 1.0000x reference)
//
#include <hip/hip_runtime.h>
#include <hip/hip_bf16.h>

#define N_NODES 50000
#define E_EDGES 800000
#define S_SAMP 4
#define D_DIM 24
#define NS (N_NODES * S_SAMP)   // 200000

// workspace layout (4-byte units)
#define OFF_AGGX  0                 // 800000 floats
#define OFF_AGGC  800000            // 1600000 floats
#define OFF_STATS 2400000           // 512 floats
// stats: [256:320) scale_s [320:384) shift_s [384:448) scale_a [448:512) shift_a
#define OFF_GRAM  2400512           // 648 floats
// gram: [0:136) s_xx tri16 (x4 applied) [136:264) s_xc 16x8 [264:300) s_cc tri8
//       [300:600) a tri24 [600:616) colsum_x (x4) [616:624) colsum_c [624:648) colsum_a
#define OFF_DEG   2401160           // 50000 ints
#define OFF_CNT   2451160           // 16 ints   (memset covers stats..cnt)
#define OFF_MA    2451176           // 3200000 floats
#define OFF_OFFS  5651176           // 50000 ints
#define OFF_CUR   5701176           // 50000 ints
#define OFF_EIDX  5751176           // 800000 ints

// ---------------------------------------------------------------------------
// CSR build
// ---------------------------------------------------------------------------
__global__ __launch_bounds__(256) void hist_kernel(
    const int* __restrict__ ei, int* __restrict__ deg)
{
    int t = blockIdx.x * blockDim.x + threadIdx.x;
    if (t >= E_EDGES) return;
    atomicAdd(&deg[ei[E_EDGES + t]], 1);
}

__global__ __launch_bounds__(256) void alloc_kernel(
    const int* __restrict__ deg, int* __restrict__ offs,
    int* __restrict__ cur, int* __restrict__ counter)
{
    __shared__ int buf[256];
    __shared__ int base;
    const int t = threadIdx.x;
    const int n = blockIdx.x * 256 + t;
    const int d = (n < N_NODES) ? deg[n] : 0;
    buf[t] = d;
    __syncthreads();
    for (int off = 1; off < 256; off <<= 1) {
        int v = (t >= off) ? buf[t - off] : 0;
        __syncthreads();
        buf[t] += v;
        __syncthreads();
    }
    if (t == 255) base = atomicAdd(counter, buf[255]);
    __syncthreads();
    if (n < N_NODES) {
        int pos = base + buf[t] - d;
        offs[n] = pos;
        cur[n] = pos;
    }
}

__global__ __launch_bounds__(256) void fill_kernel(
    const int* __restrict__ ei, int* __restrict__ cur, int* __restrict__ eidx)
{
    int t = blockIdx.x * blockDim.x + threadIdx.x;
    if (t >= E_EDGES) return;
    int s = ei[t];
    int d = ei[E_EDGES + t];
    int pos = atomicAdd(&cur[d], 1);
    eidx[pos] = s;
}

// ---------------------------------------------------------------------------
// Gather: one wave per node; lanes 0..15 -> x cols, 16..47 -> c cols.
// ---------------------------------------------------------------------------
__global__ __launch_bounds__(256) void gather_kernel(
    const float* __restrict__ x,
    const float* __restrict__ c,
    const int* __restrict__ eidx,
    const int* __restrict__ offs,
    const int* __restrict__ deg,
    float* __restrict__ aggx,
    float* __restrict__ aggc)
{
    const int wave = (blockIdx.x * blockDim.x + threadIdx.x) >> 6;
    const int lane = threadIdx.x & 63;
    if (wave >= N_NODES) return;
    const int n = wave;
    const int start = offs[n];
    const int d = deg[n];

    float acc = 0.f;
    if (lane < 48) {
        const int strd = (lane < 16) ? 16 : 32;
        const float* bp = (lane < 16) ? (x + lane) : (c + lane - 16);
        const int* ep = eidx + start;
#pragma unroll 4
        for (int i = 0; i < d; ++i) {
            int s = ep[i];
            acc += bp[(long long)s * strd];
        }
    }
    if (lane < 16)      aggx[n * 16 + lane] = acc;
    else if (lane < 48) aggc[n * 32 + (lane - 16)] = acc;
}

// ---------------------------------------------------------------------------
// Gram accumulation: BN sum/sumsq are linear/quadratic in z1 = M@W1+b, so we
// only need colsum(M) and G = M^T M. Per-node structure (x shared over the 4
// samples) cuts s-path Gram to ~400 FMA/node vs 6144 for direct z1 stats.
// One block = 64 nodes (grid 784 covers 50176). LDS stride 84 per node:
// [0:16) x~(e1s) [16:48) c~ (4x8, e1s) [48:56) sumc~ [56:80) a~(e1a) [80] 1.0
// ---------------------------------------------------------------------------
__device__ __forceinline__ void tri_invert(int u, int n, int& i, int& j)
{
    i = 0;
    while (u >= n - i) { u -= (n - i); ++i; }
    j = i + u;
}

__global__ __launch_bounds__(256) void gram_kernel(
    const float* __restrict__ x,
    const float* __restrict__ c,
    const float* __restrict__ aggx,
    const float* __restrict__ aggc,
    const float* __restrict__ epsS,
    const float* __restrict__ epsA,
    float* __restrict__ gram)
{
    __shared__ float L[64 * 84];
    const int tid = threadIdx.x;
    const float e1s = 1.0f + epsS[0];
    const float e1a = 1.0f + epsA[0];
    const int nbase = blockIdx.x * 64;

    // decode up to 3 tasks for this thread (uniform over the node loop)
    int aoff[3], boff[3];
    bool is_cc[3], valid[3];
    float mult[3];
#pragma unroll
    for (int sl = 0; sl < 3; ++sl) {
        int t = tid + sl * 256;
        valid[sl] = (t < 648);
        is_cc[sl] = false;
        mult[sl] = 1.f;
        aoff[sl] = 0; boff[sl] = 80;
        if (t < 136) {                       // s_xx tri16
            int i, j; tri_invert(t, 16, i, j);
            aoff[sl] = i; boff[sl] = j; mult[sl] = 4.f;
        } else if (t < 264) {                // s_xc
            int u = t - 136;
            aoff[sl] = u >> 3; boff[sl] = 48 + (u & 7);
        } else if (t < 300) {                // s_cc tri8 (sum over 4 samples)
            int k, l; tri_invert(t - 264, 8, k, l);
            aoff[sl] = 16 + k; boff[sl] = 16 + l; is_cc[sl] = true;
        } else if (t < 600) {                // a tri24
            int i, j; tri_invert(t - 300, 24, i, j);
            aoff[sl] = 56 + i; boff[sl] = 56 + j;
        } else if (t < 616) {                // colsum_x
            aoff[sl] = t - 600; mult[sl] = 4.f;
        } else if (t < 624) {                // colsum_c
            aoff[sl] = 48 + (t - 616);
        } else if (valid[sl]) {              // colsum_a
            aoff[sl] = 56 + (t - 624);
        }
    }

    // stage 64 nodes
    for (int i = tid; i < 64 * 16; i += 256) {       // x~ and a~ x-part
        int n = i >> 4, j = i & 15;
        int gn = nbase + n;
        float xv = 0.f, av = 0.f;
        if (gn < N_NODES) { xv = x[gn * 16 + j]; av = aggx[gn * 16 + j]; }
        L[n * 84 + j] = fmaf(e1s, xv, av);
        L[n * 84 + 56 + j] = fmaf(e1a, xv, av);
    }
    for (int i = tid; i < 64 * 32; i += 256) {       // c~
        int n = i >> 5, j = i & 31;
        int gn = nbase + n;
        float cv = 0.f, acv = 0.f;
        if (gn < N_NODES) { cv = c[gn * 32 + j]; acv = aggc[gn * 32 + j]; }
        L[n * 84 + 16 + j] = fmaf(e1s, cv, acv);
    }
    for (int i = tid; i < 64 * 8; i += 256) {        // sumc~ and a~ c-part
        int n = i >> 3, k = i & 7;
        int gn = nbase + n;
        float sc = 0.f, sa = 0.f;
        if (gn < N_NODES) {
#pragma unroll
            for (int s = 0; s < 4; ++s) {
                sc += c[gn * 32 + s * 8 + k];
                sa += aggc[gn * 32 + s * 8 + k];
            }
        }
        L[n * 84 + 48 + k] = fmaf(e1s, sc, sa);
        L[n * 84 + 72 + k] = 0.25f * fmaf(e1a, sc, sa);
    }
    for (int i = tid; i < 64; i += 256)
        L[i * 84 + 80] = 1.0f;
    __syncthreads();

    float acc[3] = {0.f, 0.f, 0.f};
    for (int nn = 0; nn < 64; ++nn) {
        int base = nn * 84;
#pragma unroll
        for (int sl = 0; sl < 3; ++sl) {
            if (!valid[sl]) continue;
            if (is_cc[sl]) {
#pragma unroll
                for (int s = 0; s < 4; ++s)
                    acc[sl] = fmaf(L[base + aoff[sl] + 8 * s],
                                   L[base + boff[sl] + 8 * s], acc[sl]);
            } else {
                acc[sl] = fmaf(L[base + aoff[sl]], L[base + boff[sl]], acc[sl]);
            }
        }
    }
#pragma unroll
    for (int sl = 0; sl < 3; ++sl)
        if (valid[sl]) atomicAdd(&gram[tid + sl * 256], acc[sl] * mult[sl]);
}

// ---------------------------------------------------------------------------
// Finalize: per column e, per path p: sum = cs.w + cnt*b ; sumsq = w'Gw +
// 2b(cs.w) + cnt*b^2 -> scale/shift. 128 threads (wave0 = shared, wave1 = agg)
// ---------------------------------------------------------------------------
__global__ void bn_finalize_kernel(
    const float* __restrict__ gram,
    const float* __restrict__ w1s, const float* __restrict__ b1s,
    const float* __restrict__ g1s, const float* __restrict__ be1s,
    const float* __restrict__ w1a, const float* __restrict__ b1a,
    const float* __restrict__ g1a, const float* __restrict__ be1a,
    float* __restrict__ stats)
{
    __shared__ float G[648];
    const int tid = threadIdx.x;
    for (int i = tid; i < 648; i += 128) G[i] = gram[i];
    __syncthreads();

    const int p = tid >> 6;
    const int e = tid & 63;
    const float* w1 = p ? w1a : w1s;
    float wr[24];
#pragma unroll
    for (int j = 0; j < 24; ++j) wr[j] = w1[j * 64 + e];
    const float b = (p ? b1a : b1s)[e];
    const float cnt = p ? (float)N_NODES : (float)NS;

    float cw = 0.f;
    if (!p) {
#pragma unroll
        for (int j = 0; j < 16; ++j) cw = fmaf(G[600 + j], wr[j], cw);
#pragma unroll
        for (int k = 0; k < 8; ++k) cw = fmaf(G[616 + k], wr[16 + k], cw);
    } else {
#pragma unroll
        for (int j = 0; j < 24; ++j) cw = fmaf(G[624 + j], wr[j], cw);
    }

    float q = 0.f;
    if (!p) {
        int idx = 0;
        for (int i = 0; i < 16; ++i)
            for (int j = i; j < 16; ++j, ++idx) {
                float coef = (i == j) ? 1.f : 2.f;
                q = fmaf(coef * G[idx], wr[i] * wr[j], q);
            }
        for (int i = 0; i < 16; ++i)
#pragma unroll
            for (int k = 0; k < 8; ++k)
                q = fmaf(2.f * G[136 + i * 8 + k], wr[i] * wr[16 + k], q);
        idx = 264;
        for (int k = 0; k < 8; ++k)
            for (int l = k; l < 8; ++l, ++idx) {
                float coef = (k == l) ? 1.f : 2.f;
                q = fmaf(coef * G[idx], wr[16 + k] * wr[16 + l], q);
            }
    } else {
        int idx = 300;
        for (int i = 0; i < 24; ++i)
            for (int j = i; j < 24; ++j, ++idx) {
                float coef = (i == j) ? 1.f : 2.f;
                q = fmaf(coef * G[idx], wr[i] * wr[j], q);
            }
    }

    float ssum = cw + cnt * b;
    float sq = q + 2.f * b * cw + cnt * b * b;
    float mu = ssum / cnt;
    float var = sq / cnt - mu * mu;
    float rstd = rsqrtf(var + 1e-5f);
    float g = (p ? g1a : g1s)[e];
    float be = (p ? be1a : be1s)[e];
    float sc = g * rstd;
    stats[256 + p * 128 + e] = sc;
    stats[256 + p * 128 + 64 + e] = fmaf(-mu, sc, be);
}

// ---------------------------------------------------------------------------
// Agg path MLP: 64 nodes per block -> ma [N,64]
// ---------------------------------------------------------------------------
__global__ __launch_bounds__(256) void mlp2_agg_kernel(
    const float* __restrict__ x,
    const float* __restrict__ c,
    const float* __restrict__ aggx,
    const float* __restrict__ aggc,
    const float* __restrict__ w1a,
    const float* __restrict__ b1a,
    const float* __restrict__ epsA,
    const float* __restrict__ stats,
    const float* __restrict__ w2a,
    const float* __restrict__ b2a,
    float* __restrict__ ma)
{
    __shared__ float sMa[64][28];
    __shared__ float sHa[64 * 64];

    const int tid = threadIdx.x;
    const float e1a = 1.0f + epsA[0];
    const int nbase = blockIdx.x * 64;
    const int e = tid & 63;
    const int rg = tid >> 6;

    for (int i = tid; i < 64 * 24; i += 256) {
        int r = i / 24, j = i % 24;
        int n = nbase + r;
        float v = 0.f;
        if (n < N_NODES) {
            if (j < 16) v = fmaf(e1a, x[n * 16 + j], aggx[n * 16 + j]);
            else {
                int kk = j - 16;
                float sc = 0.f, sa = 0.f;
#pragma unroll
                for (int s = 0; s < 4; ++s) {
                    sc += c[n * 32 + s * 8 + kk];
                    sa += aggc[n * 32 + s * 8 + kk];
                }
                v = 0.25f * fmaf(e1a, sc, sa);
            }
        }
        sMa[r][j] = v;
    }
    __syncthreads();

    {
        float wr[D_DIM];
#pragma unroll
        for (int j = 0; j < D_DIM; ++j) wr[j] = w1a[j * 64 + e];
        const float bb = b1a[e];
        const float sce = stats[384 + e], she = stats[448 + e];
#pragma unroll
        for (int r = rg; r < 64; r += 4) {
            float a0 = 0.f, a1 = 0.f, a2 = 0.f, a3 = 0.f;
#pragma unroll
            for (int j = 0; j < 6; ++j) {
                a0 = fmaf(sMa[r][j],      wr[j],      a0);
                a1 = fmaf(sMa[r][j + 6],  wr[j + 6],  a1);
                a2 = fmaf(sMa[r][j + 12], wr[j + 12], a2);
                a3 = fmaf(sMa[r][j + 18], wr[j + 18], a3);
            }
            float acc = bb + ((a0 + a1) + (a2 + a3));
            sHa[r * 64 + e] = fmaxf(fmaf(acc, sce, she), 0.f);
        }
    }
    __syncthreads();

    {
        float wr[64];
#pragma unroll
        for (int k = 0; k < 64; ++k) wr[k] = w2a[k * 64 + e];
        const float bb = b2a[e];
#pragma unroll
        for (int r = rg; r < 64; r += 4) {
            int n = nbase + r;
            if (n >= N_NODES) break;
            float a0 = 0.f, a1 = 0.f, a2 = 0.f, a3 = 0.f;
#pragma unroll
            for (int k = 0; k < 16; ++k) {
                a0 = fmaf(sHa[r * 64 + k],      wr[k],      a0);
                a1 = fmaf(sHa[r * 64 + k + 16], wr[k + 16], a1);
                a2 = fmaf(sHa[r * 64 + k + 32], wr[k + 32], a2);
                a3 = fmaf(sHa[r * 64 + k + 48], wr[k + 48], a3);
            }
            ma[n * 64 + e] = bb + ((a0 + a1) + (a2 + a3));
        }
    }
}

// ---------------------------------------------------------------------------
// Shared path MLP + DSS combine: 64 rows (=16 nodes) per block, exact grid.
// ma read from global in epilogue (coalesced).
// ---------------------------------------------------------------------------
__global__ __launch_bounds__(256) void mlp2_shared_kernel(
    const float* __restrict__ x,
    const float* __restrict__ c,
    const float* __restrict__ aggx,
    const float* __restrict__ aggc,
    const float* __restrict__ w1s,
    const float* __restrict__ b1s,
    const float* __restrict__ epsS,
    const float* __restrict__ stats,
    const float* __restrict__ w2s,
    const float* __restrict__ b2s,
    const float* __restrict__ ma,
    float* __restrict__ out)
{
    __shared__ float sM[64][28];
    __shared__ float sH[64 * 64];

    const int tid = threadIdx.x;
    const float e1s = 1.0f + epsS[0];
    const int r0 = blockIdx.x * 64;
    const int e = tid & 63;
    const int rg = tid >> 6;

    for (int i = tid; i < 64 * 24; i += 256) {
        int r = i / 24, j = i % 24;
        int rw = r0 + r;
        int n = rw >> 2;
        int s = rw & 3;
        float v;
        if (j < 16) v = fmaf(e1s, x[n * 16 + j], aggx[n * 16 + j]);
        else {
            int kk = j - 16;
            v = fmaf(e1s, c[n * 32 + s * 8 + kk], aggc[n * 32 + s * 8 + kk]);
        }
        sM[r][j] = v;
    }
    __syncthreads();

    {
        float wr[D_DIM];
#pragma unroll
        for (int j = 0; j < D_DIM; ++j) wr[j] = w1s[j * 64 + e];
        const float bb = b1s[e];
        const float sce = stats[256 + e], she = stats[320 + e];
#pragma unroll
        for (int r = rg; r < 64; r += 4) {
            float a0 = 0.f, a1 = 0.f, a2 = 0.f, a3 = 0.f;
#pragma unroll
            for (int j = 0; j < 6; ++j) {
                a0 = fmaf(sM[r][j],      wr[j],      a0);
                a1 = fmaf(sM[r][j + 6],  wr[j + 6],  a1);
                a2 = fmaf(sM[r][j + 12], wr[j + 12], a2);
                a3 = fmaf(sM[r][j + 18], wr[j + 18], a3);
            }
            float acc = bb + ((a0 + a1) + (a2 + a3));
            sH[r * 64 + e] = fmaxf(fmaf(acc, sce, she), 0.f);
        }
    }
    __syncthreads();

    {
        float wr[64];
#pragma unroll
        for (int k = 0; k < 64; ++k) wr[k] = w2s[k * 64 + e];
        const float bb = b2s[e];
#pragma unroll
        for (int r = rg; r < 64; r += 4) {
            int rw = r0 + r;
            float a0 = 0.f, a1 = 0.f, a2 = 0.f, a3 = 0.f;
#pragma unroll
            for (int k = 0; k < 16; ++k) {
                a0 = fmaf(sH[r * 64 + k],      wr[k],      a0);
                a1 = fmaf(sH[r * 64 + k + 16], wr[k + 16], a1);
                a2 = fmaf(sH[r * 64 + k + 32], wr[k + 32], a2);
                a3 = fmaf(sH[r * 64 + k + 48], wr[k + 48], a3);
            }
            float acc = bb + ma[(rw >> 2) * 64 + e] + ((a0 + a1) + (a2 + a3));
            out[rw * 64 + e] = acc;
        }
    }
}

// ---------------------------------------------------------------------------
extern "C" void kernel_launch(void* const* d_in, const int* in_sizes, int n_in,
                              void* d_out, int out_size, void* d_ws, size_t ws_size,
                              hipStream_t stream)
{
    const float* x    = (const float*)d_in[0];
    const float* c    = (const float*)d_in[1];
    const int*   ei   = (const int*)d_in[2];
    const float* epsS = (const float*)d_in[3];
    const float* W1s  = (const float*)d_in[4];
    const float* b1s  = (const float*)d_in[5];
    const float* g1s  = (const float*)d_in[6];
    const float* be1s = (const float*)d_in[7];
    const float* W2s  = (const float*)d_in[8];
    const float* b2s  = (const float*)d_in[9];
    const float* epsA = (const float*)d_in[10];
    const float* W1a  = (const float*)d_in[11];
    const float* b1a  = (const float*)d_in[12];
    const float* g1a  = (const float*)d_in[13];
    const float* be1a = (const float*)d_in[14];
    const float* W2a  = (const float*)d_in[15];
    const float* b2a  = (const float*)d_in[16];

    float* ws    = (float*)d_ws;
    float* aggx  = ws + OFF_AGGX;
    float* aggc  = ws + OFF_AGGC;
    float* stats = ws + OFF_STATS;
    float* gram  = ws + OFF_GRAM;
    float* ma    = ws + OFF_MA;
    int*   deg   = (int*)ws + OFF_DEG;
    int*   cnt   = (int*)ws + OFF_CNT;
    int*   offs  = (int*)ws + OFF_OFFS;
    int*   cur   = (int*)ws + OFF_CUR;
    int*   eidx  = (int*)ws + OFF_EIDX;

    // zero stats + gram + deg + counter (contiguous)
    hipMemsetAsync(stats, 0, (size_t)(512 + 648 + N_NODES + 16) * sizeof(float), stream);

    // CSR build + gather
    hist_kernel<<<(E_EDGES + 255) / 256, 256, 0, stream>>>(ei, deg);
    alloc_kernel<<<(N_NODES + 255) / 256, 256, 0, stream>>>(deg, offs, cur, cnt);
    fill_kernel<<<(E_EDGES + 255) / 256, 256, 0, stream>>>(ei, cur, eidx);
    gather_kernel<<<(N_NODES * 64 + 255) / 256, 256, 0, stream>>>(
        x, c, eidx, offs, deg, aggx, aggc);

    // Gram-based BN stats
    gram_kernel<<<784, 256, 0, stream>>>(x, c, aggx, aggc, epsS, epsA, gram);
    bn_finalize_kernel<<<1, 128, 0, stream>>>(
        gram, W1s, b1s, g1s, be1s, W1a, b1a, g1a, be1a, stats);

    // MLPs
    mlp2_agg_kernel<<<(N_NODES + 63) / 64, 256, 0, stream>>>(
        x, c, aggx, aggc, W1a, b1a, epsA, stats, W2a, b2a, ma);
    mlp2_shared_kernel<<<NS / 64, 256, 0, stream>>>(
        x, c, aggx, aggc, W1s, b1s, epsS, stats, W2s, b2s, ma, (float*)d_out);
}